// Round 1
// baseline (1722.971 us; speedup 1.0000x reference)
//
#include <hip/hip_runtime.h>
#include <cmath>

// Problem constants
#define BB   8192
#define ZD   16
#define HHID 64
#define DH   1024
#define DX   3072
#define M2   (2*BB)

static constexpr float LOG2PI_F = 1.8378770664093453f;   // log(2*pi)
static constexpr float CLAMP_F  = 1000000.0f;

__device__ __forceinline__ float clampv(float x){
    // nan_to_num not needed on these paths (all finite), clip only
    return fminf(fmaxf(x, -CLAMP_F), CLAMP_F);
}

// ---------------------------------------------------------------------------
// Accumulator init / finalize
// ---------------------------------------------------------------------------
__global__ void init_acc(double* acc){
    if (threadIdx.x == 0) acc[0] = 0.0;
}

__global__ void finalize_kernel(const double* __restrict__ acc, float* __restrict__ out){
    if (threadIdx.x == 0){
        const double LOG17 = 2.8332133440562162; // log(17)
        const double log_p_I = -LOG17 * (double)BB;
        out[(size_t)2 * BB * DX] = (float)(acc[0] + log_p_I);
    }
}

// ---------------------------------------------------------------------------
// Flow network: per (i in 0..15, b in 0..8191):
//   ctx = e1[b,:] with element i zeroed
//   h1 = relu(ctx @ W1[i] + b1[i])          (64)
//   h2 = relu(h1 @ W2[i] + b2[i])           (64)
//   p  = h2 @ W3[i] + b3[i]                 (2)
//   shift=p0, scale=softplus(p1)+0.2
//   z=(e2[b,i]-shift)/scale
//   term = (-0.5 z^2 - 0.5 log2pi - log scale) * intervention[b, i+1]
// Also (i==0 blocks) accumulate sum of std-normal logprob of e1.
// Weight reads are thread-uniform -> compiler promotes to scalar loads.
// ---------------------------------------------------------------------------
__global__ __launch_bounds__(256)
void flow_kernel(const float* __restrict__ e1, const float* __restrict__ e2,
                 const float* __restrict__ interv,
                 const float* __restrict__ W1, const float* __restrict__ b1,
                 const float* __restrict__ W2, const float* __restrict__ b2,
                 const float* __restrict__ W3, const float* __restrict__ b3,
                 double* __restrict__ acc)
{
    const int i = blockIdx.y;                       // 0..15
    const int b = blockIdx.x * 256 + threadIdx.x;   // 0..8191

    float ex[16];
    #pragma unroll
    for (int d = 0; d < 16; d += 4){
        const float4 v = *reinterpret_cast<const float4*>(&e1[(size_t)b*16 + d]);
        ex[d] = v.x; ex[d+1] = v.y; ex[d+2] = v.z; ex[d+3] = v.w;
    }

    float lp1 = 0.f;
    if (i == 0){
        #pragma unroll
        for (int d = 0; d < 16; ++d){
            const float t = -0.5f*ex[d]*ex[d] - 0.5f*LOG2PI_F;
            lp1 += clampv(t);
        }
    }

    // zero out context element i (in place; lp1 already computed)
    #pragma unroll
    for (int d = 0; d < 16; ++d)
        if (d == i) ex[d] = 0.f;

    // h1 = relu(ctx @ W1[i] + b1[i])
    float h1[64];
    #pragma unroll
    for (int h = 0; h < 64; h += 4){
        const float4 bv = *reinterpret_cast<const float4*>(&b1[i*64 + h]);
        h1[h] = bv.x; h1[h+1] = bv.y; h1[h+2] = bv.z; h1[h+3] = bv.w;
    }
    for (int d = 0; d < 16; ++d){
        const float c = ex[d];
        const float* w = &W1[((size_t)i*16 + d)*64];
        #pragma unroll
        for (int h = 0; h < 64; h += 4){
            const float4 wv = *reinterpret_cast<const float4*>(&w[h]);
            h1[h]   = fmaf(c, wv.x, h1[h]);
            h1[h+1] = fmaf(c, wv.y, h1[h+1]);
            h1[h+2] = fmaf(c, wv.z, h1[h+2]);
            h1[h+3] = fmaf(c, wv.w, h1[h+3]);
        }
    }
    #pragma unroll
    for (int h = 0; h < 64; ++h) h1[h] = fmaxf(h1[h], 0.f);

    // h2 accumulation (keep 64 accumulators, stream h)
    float hk[64];
    #pragma unroll
    for (int k = 0; k < 64; k += 4){
        const float4 bv = *reinterpret_cast<const float4*>(&b2[i*64 + k]);
        hk[k] = bv.x; hk[k+1] = bv.y; hk[k+2] = bv.z; hk[k+3] = bv.w;
    }
    for (int h = 0; h < 64; ++h){
        const float hv = h1[h];
        const float* w = &W2[((size_t)i*64 + h)*64];
        #pragma unroll
        for (int k = 0; k < 64; k += 4){
            const float4 wv = *reinterpret_cast<const float4*>(&w[k]);
            hk[k]   = fmaf(hv, wv.x, hk[k]);
            hk[k+1] = fmaf(hv, wv.y, hk[k+1]);
            hk[k+2] = fmaf(hv, wv.z, hk[k+2]);
            hk[k+3] = fmaf(hv, wv.w, hk[k+3]);
        }
    }
    #pragma unroll
    for (int k = 0; k < 64; ++k) hk[k] = fmaxf(hk[k], 0.f);

    float p0 = b3[i*2 + 0];
    float p1 = b3[i*2 + 1];
    for (int k = 0; k < 64; ++k){
        const float2 wv = *reinterpret_cast<const float2*>(&W3[((size_t)i*64 + k)*2]);
        p0 = fmaf(hk[k], wv.x, p0);
        p1 = fmaf(hk[k], wv.y, p1);
    }

    const float shift = p0;
    const float sp    = (p1 > 20.f) ? p1 : log1pf(expf(p1));
    const float scale = sp + 0.2f;
    float z = (e2[(size_t)b*16 + i] - shift) / scale;
    z = clampv(z);
    const float mask = interv[(size_t)b*17 + i + 1];
    const float term = (-0.5f*z*z - 0.5f*LOG2PI_F - logf(scale)) * mask;

    double v = (double)term + (double)lp1;

    // wave (64) + block reduce in double, one atomic per block
    #pragma unroll
    for (int off = 32; off; off >>= 1) v += __shfl_down(v, off, 64);
    __shared__ double sred[4];
    if ((threadIdx.x & 63) == 0) sred[threadIdx.x >> 6] = v;
    __syncthreads();
    if (threadIdx.x == 0){
        const double s = sred[0] + sred[1] + sred[2] + sred[3];
        atomicAdd(acc, s);
    }
}

// ---------------------------------------------------------------------------
// Decoder layer 1: hh1 = relu(E @ Wd1 + bd1); E = concat(e1, e2) (16384 x 16)
// one block per row; 256 threads x float4 cols
// ---------------------------------------------------------------------------
__global__ __launch_bounds__(256)
void dec1_kernel(const float* __restrict__ e1, const float* __restrict__ e2,
                 const float* __restrict__ Wd1, const float* __restrict__ bd1,
                 float* __restrict__ hh1)
{
    const int r = blockIdx.x;
    const float* e = (r < BB) ? &e1[(size_t)r*16] : &e2[(size_t)(r - BB)*16];
    const int col = threadIdx.x * 4;
    float4 a = *reinterpret_cast<const float4*>(&bd1[col]);
    #pragma unroll
    for (int d = 0; d < 16; ++d){
        const float ev = e[d];  // uniform across the block -> scalar load
        const float4 w = *reinterpret_cast<const float4*>(&Wd1[(size_t)d*DH + col]);
        a.x = fmaf(ev, w.x, a.x);
        a.y = fmaf(ev, w.y, a.y);
        a.z = fmaf(ev, w.z, a.z);
        a.w = fmaf(ev, w.w, a.w);
    }
    a.x = fmaxf(a.x, 0.f); a.y = fmaxf(a.y, 0.f);
    a.z = fmaxf(a.z, 0.f); a.w = fmaxf(a.w, 0.f);
    *reinterpret_cast<float4*>(&hh1[(size_t)r*DH + col]) = a;
}

// ---------------------------------------------------------------------------
// fp32 tiled GEMM: C(MxN) = A(MxK) @ B(KxN) + bias, optional relu.
// 128x128 tile, 256 threads, 8x8 micro-tile, K-step 16.
// ---------------------------------------------------------------------------
template<int RELU>
__global__ __launch_bounds__(256)
void gemm_bias(const float* __restrict__ A, const float* __restrict__ Bm,
               const float* __restrict__ bias, float* __restrict__ C,
               int M, int N, int K)
{
    __shared__ float As[16][128];   // [kk][row]
    __shared__ float Bs[16][128];   // [kk][col]

    const int tid  = threadIdx.x;
    const int tx   = tid & 15;
    const int ty   = tid >> 4;
    const int brow = blockIdx.y * 128;
    const int bcol = blockIdx.x * 128;

    float acc[8][8];
    #pragma unroll
    for (int r = 0; r < 8; ++r)
        #pragma unroll
        for (int c = 0; c < 8; ++c) acc[r][c] = 0.f;

    const int arow = tid >> 1;           // 0..127
    const int akq  = (tid & 1) * 8;      // 0 or 8
    const int bkk  = tid >> 5;           // 0..7
    const int bc4  = (tid & 31) * 4;     // 0,4,..,124

    for (int k0 = 0; k0 < K; k0 += 16){
        const float4 a0 = *reinterpret_cast<const float4*>(&A[(size_t)(brow + arow)*K + k0 + akq]);
        const float4 a1 = *reinterpret_cast<const float4*>(&A[(size_t)(brow + arow)*K + k0 + akq + 4]);
        const float4 g0 = *reinterpret_cast<const float4*>(&Bm[(size_t)(k0 + bkk)*N + bcol + bc4]);
        const float4 g1 = *reinterpret_cast<const float4*>(&Bm[(size_t)(k0 + bkk + 8)*N + bcol + bc4]);

        __syncthreads();   // previous iteration's reads done
        As[akq+0][arow] = a0.x; As[akq+1][arow] = a0.y;
        As[akq+2][arow] = a0.z; As[akq+3][arow] = a0.w;
        As[akq+4][arow] = a1.x; As[akq+5][arow] = a1.y;
        As[akq+6][arow] = a1.z; As[akq+7][arow] = a1.w;
        *reinterpret_cast<float4*>(&Bs[bkk][bc4])     = g0;
        *reinterpret_cast<float4*>(&Bs[bkk + 8][bc4]) = g1;
        __syncthreads();

        #pragma unroll
        for (int kk = 0; kk < 16; ++kk){
            const float4 av0 = *reinterpret_cast<const float4*>(&As[kk][ty*4]);
            const float4 av1 = *reinterpret_cast<const float4*>(&As[kk][ty*4 + 64]);
            const float4 bv0 = *reinterpret_cast<const float4*>(&Bs[kk][tx*4]);
            const float4 bv1 = *reinterpret_cast<const float4*>(&Bs[kk][tx*4 + 64]);
            float ar[8], br[8];
            ar[0]=av0.x; ar[1]=av0.y; ar[2]=av0.z; ar[3]=av0.w;
            ar[4]=av1.x; ar[5]=av1.y; ar[6]=av1.z; ar[7]=av1.w;
            br[0]=bv0.x; br[1]=bv0.y; br[2]=bv0.z; br[3]=bv0.w;
            br[4]=bv1.x; br[5]=bv1.y; br[6]=bv1.z; br[7]=bv1.w;
            #pragma unroll
            for (int r = 0; r < 8; ++r)
                #pragma unroll
                for (int c = 0; c < 8; ++c)
                    acc[r][c] = fmaf(ar[r], br[c], acc[r][c]);
        }
    }

    const float4 bias0 = *reinterpret_cast<const float4*>(&bias[bcol + tx*4]);
    const float4 bias1 = *reinterpret_cast<const float4*>(&bias[bcol + 64 + tx*4]);

    #pragma unroll
    for (int rr = 0; rr < 8; ++rr){
        const int row = brow + ((rr < 4) ? (ty*4 + rr) : (64 + ty*4 + (rr - 4)));
        float4 o0, o1;
        o0.x = acc[rr][0] + bias0.x; o0.y = acc[rr][1] + bias0.y;
        o0.z = acc[rr][2] + bias0.z; o0.w = acc[rr][3] + bias0.w;
        o1.x = acc[rr][4] + bias1.x; o1.y = acc[rr][5] + bias1.y;
        o1.z = acc[rr][6] + bias1.z; o1.w = acc[rr][7] + bias1.w;
        if (RELU){
            o0.x = fmaxf(o0.x, 0.f); o0.y = fmaxf(o0.y, 0.f);
            o0.z = fmaxf(o0.z, 0.f); o0.w = fmaxf(o0.w, 0.f);
            o1.x = fmaxf(o1.x, 0.f); o1.y = fmaxf(o1.y, 0.f);
            o1.z = fmaxf(o1.z, 0.f); o1.w = fmaxf(o1.w, 0.f);
        }
        *reinterpret_cast<float4*>(&C[(size_t)row*N + bcol + tx*4])      = o0;
        *reinterpret_cast<float4*>(&C[(size_t)row*N + bcol + 64 + tx*4]) = o1;
    }
}

// ---------------------------------------------------------------------------
// launcher
// ---------------------------------------------------------------------------
extern "C" void kernel_launch(void* const* d_in, const int* in_sizes, int n_in,
                              void* d_out, int out_size, void* d_ws, size_t ws_size,
                              hipStream_t stream)
{
    const float* e1     = (const float*)d_in[0];
    const float* e2     = (const float*)d_in[1];
    const float* interv = (const float*)d_in[2];
    const float* W1     = (const float*)d_in[3];
    const float* b1     = (const float*)d_in[4];
    const float* W2     = (const float*)d_in[5];
    const float* b2     = (const float*)d_in[6];
    const float* W3     = (const float*)d_in[7];
    const float* b3     = (const float*)d_in[8];
    const float* Wd1    = (const float*)d_in[9];
    const float* bd1    = (const float*)d_in[10];
    const float* Wd2    = (const float*)d_in[11];
    const float* bd2    = (const float*)d_in[12];
    const float* Wd3    = (const float*)d_in[13];
    const float* bd3    = (const float*)d_in[14];

    float*  out = (float*)d_out;
    double* acc = (double*)d_ws;                       // 8B accumulator
    float*  hh2 = (float*)((char*)d_ws + 256);         // 16384x1024 fp32 (64 MB)
    float*  hh1 = out;                                 // scratch inside d_out
                                                       // (overwritten by GEMM3 later)

    hipLaunchKernelGGL(init_acc, dim3(1), dim3(64), 0, stream, acc);

    hipLaunchKernelGGL(flow_kernel, dim3(BB/256, ZD), dim3(256), 0, stream,
                       e1, e2, interv, W1, b1, W2, b2, W3, b3, acc);

    hipLaunchKernelGGL(dec1_kernel, dim3(M2), dim3(256), 0, stream,
                       e1, e2, Wd1, bd1, hh1);

    hipLaunchKernelGGL((gemm_bias<1>), dim3(DH/128, M2/128), dim3(256), 0, stream,
                       hh1, Wd2, bd2, hh2, M2, DH, DH);

    hipLaunchKernelGGL((gemm_bias<0>), dim3(DX/128, M2/128), dim3(256), 0, stream,
                       hh2, Wd3, bd3, out, M2, DX, DH);

    hipLaunchKernelGGL(finalize_kernel, dim3(1), dim3(64), 0, stream, acc, out);
}

// Round 2
// 509.560 us; speedup vs baseline: 3.3813x; 3.3813x over previous
//
#include <hip/hip_runtime.h>
#include <cmath>

// Problem constants
#define BB   8192
#define ZD   16
#define DH   1024
#define DX   3072
#define M2   (2*BB)

static constexpr float LOG2PI_F = 1.8378770664093453f;   // log(2*pi)
static constexpr float CLAMP_F  = 1000000.0f;

using half8  = __attribute__((ext_vector_type(8))) _Float16;
using half4v = __attribute__((ext_vector_type(4))) _Float16;
using f32x4  = __attribute__((ext_vector_type(4))) float;

__device__ __forceinline__ float clampv(float x){
    return fminf(fmaxf(x, -CLAMP_F), CLAMP_F);
}

// async global->LDS, 16B per lane. Per-lane global src; LDS dest is
// wave-uniform base + lane*16 (we pass the per-lane address which equals that).
__device__ __forceinline__ void gload_lds16(const void* g, void* l){
    __builtin_amdgcn_global_load_lds(
        (const __attribute__((address_space(1))) unsigned int*)g,
        (__attribute__((address_space(3))) unsigned int*)l,
        16, 0, 0);
}

// ---------------------------------------------------------------------------
// Accumulator init / finalize
// ---------------------------------------------------------------------------
__global__ void init_acc(double* acc){
    if (threadIdx.x == 0) acc[0] = 0.0;
}

__global__ void finalize_kernel(const double* __restrict__ acc, float* __restrict__ out){
    if (threadIdx.x == 0){
        const double LOG17 = 2.8332133440562162; // log(17)
        const double log_p_I = -LOG17 * (double)BB;
        out[(size_t)2 * BB * DX] = (float)(acc[0] + log_p_I);
    }
}

// ---------------------------------------------------------------------------
// Flow network (unchanged from round 1 — not a top dispatch)
// ---------------------------------------------------------------------------
__global__ __launch_bounds__(256)
void flow_kernel(const float* __restrict__ e1, const float* __restrict__ e2,
                 const float* __restrict__ interv,
                 const float* __restrict__ W1, const float* __restrict__ b1,
                 const float* __restrict__ W2, const float* __restrict__ b2,
                 const float* __restrict__ W3, const float* __restrict__ b3,
                 double* __restrict__ acc)
{
    const int i = blockIdx.y;
    const int b = blockIdx.x * 256 + threadIdx.x;

    float ex[16];
    #pragma unroll
    for (int d = 0; d < 16; d += 4){
        const float4 v = *reinterpret_cast<const float4*>(&e1[(size_t)b*16 + d]);
        ex[d] = v.x; ex[d+1] = v.y; ex[d+2] = v.z; ex[d+3] = v.w;
    }

    float lp1 = 0.f;
    if (i == 0){
        #pragma unroll
        for (int d = 0; d < 16; ++d){
            const float t = -0.5f*ex[d]*ex[d] - 0.5f*LOG2PI_F;
            lp1 += clampv(t);
        }
    }

    #pragma unroll
    for (int d = 0; d < 16; ++d)
        if (d == i) ex[d] = 0.f;

    float h1[64];
    #pragma unroll
    for (int h = 0; h < 64; h += 4){
        const float4 bv = *reinterpret_cast<const float4*>(&b1[i*64 + h]);
        h1[h] = bv.x; h1[h+1] = bv.y; h1[h+2] = bv.z; h1[h+3] = bv.w;
    }
    for (int d = 0; d < 16; ++d){
        const float c = ex[d];
        const float* w = &W1[((size_t)i*16 + d)*64];
        #pragma unroll
        for (int h = 0; h < 64; h += 4){
            const float4 wv = *reinterpret_cast<const float4*>(&w[h]);
            h1[h]   = fmaf(c, wv.x, h1[h]);
            h1[h+1] = fmaf(c, wv.y, h1[h+1]);
            h1[h+2] = fmaf(c, wv.z, h1[h+2]);
            h1[h+3] = fmaf(c, wv.w, h1[h+3]);
        }
    }
    #pragma unroll
    for (int h = 0; h < 64; ++h) h1[h] = fmaxf(h1[h], 0.f);

    float hk[64];
    #pragma unroll
    for (int k = 0; k < 64; k += 4){
        const float4 bv = *reinterpret_cast<const float4*>(&b2[i*64 + k]);
        hk[k] = bv.x; hk[k+1] = bv.y; hk[k+2] = bv.z; hk[k+3] = bv.w;
    }
    for (int h = 0; h < 64; ++h){
        const float hv = h1[h];
        const float* w = &W2[((size_t)i*64 + h)*64];
        #pragma unroll
        for (int k = 0; k < 64; k += 4){
            const float4 wv = *reinterpret_cast<const float4*>(&w[k]);
            hk[k]   = fmaf(hv, wv.x, hk[k]);
            hk[k+1] = fmaf(hv, wv.y, hk[k+1]);
            hk[k+2] = fmaf(hv, wv.z, hk[k+2]);
            hk[k+3] = fmaf(hv, wv.w, hk[k+3]);
        }
    }
    #pragma unroll
    for (int k = 0; k < 64; ++k) hk[k] = fmaxf(hk[k], 0.f);

    float p0 = b3[i*2 + 0];
    float p1 = b3[i*2 + 1];
    for (int k = 0; k < 64; ++k){
        const float2 wv = *reinterpret_cast<const float2*>(&W3[((size_t)i*64 + k)*2]);
        p0 = fmaf(hk[k], wv.x, p0);
        p1 = fmaf(hk[k], wv.y, p1);
    }

    const float shift = p0;
    const float sp    = (p1 > 20.f) ? p1 : log1pf(expf(p1));
    const float scale = sp + 0.2f;
    float z = (e2[(size_t)b*16 + i] - shift) / scale;
    z = clampv(z);
    const float mask = interv[(size_t)b*17 + i + 1];
    const float term = (-0.5f*z*z - 0.5f*LOG2PI_F - logf(scale)) * mask;

    double v = (double)term + (double)lp1;

    #pragma unroll
    for (int off = 32; off; off >>= 1) v += __shfl_down(v, off, 64);
    __shared__ double sred[4];
    if ((threadIdx.x & 63) == 0) sred[threadIdx.x >> 6] = v;
    __syncthreads();
    if (threadIdx.x == 0){
        const double s = sred[0] + sred[1] + sred[2] + sred[3];
        atomicAdd(acc, s);
    }
}

// ---------------------------------------------------------------------------
// Transpose + fp32->fp16 convert: Wt[n][k] = (half)W[k][n]
// 32x32 tiles via LDS
// ---------------------------------------------------------------------------
__global__ __launch_bounds__(256)
void convT_kernel(const float* __restrict__ W, _Float16* __restrict__ Wt,
                  int K, int N)
{
    __shared__ float s[32][33];
    const int n0 = blockIdx.x * 32;
    const int k0 = blockIdx.y * 32;
    const int t  = threadIdx.x;
    const int r  = t >> 3;        // 0..31
    const int c4 = (t & 7) * 4;   // 0,4,..,28

    const float4 v = *reinterpret_cast<const float4*>(&W[(size_t)(k0 + r)*N + n0 + c4]);
    s[r][c4+0] = v.x; s[r][c4+1] = v.y; s[r][c4+2] = v.z; s[r][c4+3] = v.w;
    __syncthreads();

    half4v o;
    o[0] = (_Float16)s[c4+0][r];
    o[1] = (_Float16)s[c4+1][r];
    o[2] = (_Float16)s[c4+2][r];
    o[3] = (_Float16)s[c4+3][r];
    *reinterpret_cast<half4v*>(&Wt[(size_t)(n0 + r)*K + k0 + c4]) = o;
}

// ---------------------------------------------------------------------------
// Decoder layer 1: hh1 = relu(E @ Wd1 + bd1) as fp16; E = concat(e1,e2)
// ---------------------------------------------------------------------------
__global__ __launch_bounds__(256)
void dec1_kernel(const float* __restrict__ e1, const float* __restrict__ e2,
                 const float* __restrict__ Wd1, const float* __restrict__ bd1,
                 _Float16* __restrict__ hh1)
{
    const int r = blockIdx.x;
    const float* e = (r < BB) ? &e1[(size_t)r*16] : &e2[(size_t)(r - BB)*16];
    const int col = threadIdx.x * 4;
    float4 a = *reinterpret_cast<const float4*>(&bd1[col]);
    #pragma unroll
    for (int d = 0; d < 16; ++d){
        const float ev = e[d];
        const float4 w = *reinterpret_cast<const float4*>(&Wd1[(size_t)d*DH + col]);
        a.x = fmaf(ev, w.x, a.x);
        a.y = fmaf(ev, w.y, a.y);
        a.z = fmaf(ev, w.z, a.z);
        a.w = fmaf(ev, w.w, a.w);
    }
    half4v o;
    o[0] = (_Float16)fmaxf(a.x, 0.f);
    o[1] = (_Float16)fmaxf(a.y, 0.f);
    o[2] = (_Float16)fmaxf(a.z, 0.f);
    o[3] = (_Float16)fmaxf(a.w, 0.f);
    *reinterpret_cast<half4v*>(&hh1[(size_t)r*DH + col]) = o;
}

// ---------------------------------------------------------------------------
// fp16 MFMA GEMM: C(MxN) = A(MxK) @ B(KxN) + bias, optional relu.
// A: [M][K] fp16 row-major.  Bt: [N][K] fp16 (pre-transposed).
// 128x128 tile, BK=32, 4 waves (2x2), 4x4 frags of 16x16x32 per wave.
// LDS tiles [128][32] fp16 with XOR chunk-swizzle: the 16B chunk at
// (row, slot) holds global k-chunk  c = slot ^ ((row>>1)&3).
// Applied on BOTH the global_load_lds source and the ds_read (rule #21).
// ---------------------------------------------------------------------------
template<int NRELU, int OUT_HALF>
__global__ __launch_bounds__(256)
void gemm_mfma(const _Float16* __restrict__ A,
               const _Float16* __restrict__ Bt,
               const float* __restrict__ bias,
               void* __restrict__ Cout,
               int M, int N, int K)
{
    __shared__ _Float16 As[128*32];
    __shared__ _Float16 Bs[128*32];

    const int tid  = threadIdx.x;
    const int lane = tid & 63;
    const int wid  = tid >> 6;        // 0..3
    const int wm   = wid & 1;         // wave row (0..1)
    const int wn   = wid >> 1;        // wave col (0..1)

    const int brow = blockIdx.y * 128;
    const int bcol = blockIdx.x * 128;

    f32x4 acc[4][4];
    #pragma unroll
    for (int mb = 0; mb < 4; ++mb)
        #pragma unroll
        for (int nb = 0; nb < 4; ++nb)
            acc[mb][nb] = (f32x4){0.f, 0.f, 0.f, 0.f};

    // staging lane decomposition: 16 rows x 4 chunks per instruction
    const int srow = lane >> 2;       // 0..15
    const int slot = lane & 3;        // 16B slot within the 64B row

    for (int k0 = 0; k0 < K; k0 += 32){
        #pragma unroll
        for (int t = 0; t < 2; ++t){
            const int row   = wid*32 + t*16 + srow;           // 0..127
            const int chunk = slot ^ ((row >> 1) & 3);        // inverse swizzle on src
            const _Float16* ga = A  + (size_t)(brow + row)*K + k0 + chunk*8;
            const _Float16* gb = Bt + (size_t)(bcol + row)*K + k0 + chunk*8;
            // LDS dest: linear = row*64 + slot*16 bytes == waveBase + lane*16
            gload_lds16(ga, (char*)As + row*64 + slot*16);
            gload_lds16(gb, (char*)Bs + row*64 + slot*16);
        }
        __syncthreads();   // compiler drains vmcnt before barrier -> tiles ready

        half8 af[4], bf[4];
        #pragma unroll
        for (int mb = 0; mb < 4; ++mb){
            const int row = wm*64 + mb*16 + (lane & 15);
            const int c   = (lane >> 4) ^ ((row >> 1) & 3);   // swizzled read
            af[mb] = *reinterpret_cast<const half8*>((const char*)As + row*64 + c*16);
        }
        #pragma unroll
        for (int nb = 0; nb < 4; ++nb){
            const int row = wn*64 + nb*16 + (lane & 15);
            const int c   = (lane >> 4) ^ ((row >> 1) & 3);
            bf[nb] = *reinterpret_cast<const half8*>((const char*)Bs + row*64 + c*16);
        }

        #pragma unroll
        for (int mb = 0; mb < 4; ++mb)
            #pragma unroll
            for (int nb = 0; nb < 4; ++nb)
                acc[mb][nb] = __builtin_amdgcn_mfma_f32_16x16x32_f16(
                                  af[mb], bf[nb], acc[mb][nb], 0, 0, 0);

        __syncthreads();   // all reads done before next stage overwrites
    }

    // epilogue: C/D layout col=lane&15, row=(lane>>4)*4+reg  [m89/m91]
    const int lc  = lane & 15;
    const int lr4 = (lane >> 4) * 4;
    #pragma unroll
    for (int nb = 0; nb < 4; ++nb){
        const int col = bcol + wn*64 + nb*16 + lc;
        const float bv = bias[col];
        #pragma unroll
        for (int mb = 0; mb < 4; ++mb){
            const int rowg = brow + wm*64 + mb*16 + lr4;
            #pragma unroll
            for (int r = 0; r < 4; ++r){
                float v = acc[mb][nb][r] + bv;
                if (NRELU) v = fmaxf(v, 0.f);
                if (OUT_HALF)
                    ((_Float16*)Cout)[(size_t)(rowg + r)*N + col] = (_Float16)v;
                else
                    ((float*)Cout)[(size_t)(rowg + r)*N + col] = v;
            }
        }
    }
}

// ---------------------------------------------------------------------------
// launcher
// ---------------------------------------------------------------------------
extern "C" void kernel_launch(void* const* d_in, const int* in_sizes, int n_in,
                              void* d_out, int out_size, void* d_ws, size_t ws_size,
                              hipStream_t stream)
{
    const float* e1     = (const float*)d_in[0];
    const float* e2     = (const float*)d_in[1];
    const float* interv = (const float*)d_in[2];
    const float* W1     = (const float*)d_in[3];
    const float* b1     = (const float*)d_in[4];
    const float* W2     = (const float*)d_in[5];
    const float* b2     = (const float*)d_in[6];
    const float* W3     = (const float*)d_in[7];
    const float* b3     = (const float*)d_in[8];
    const float* Wd1    = (const float*)d_in[9];
    const float* bd1    = (const float*)d_in[10];
    const float* Wd2    = (const float*)d_in[11];
    const float* bd2    = (const float*)d_in[12];
    const float* Wd3    = (const float*)d_in[13];
    const float* bd3    = (const float*)d_in[14];

    float* out = (float*)d_out;

    // workspace map (~40.25 MB; proven >= 64 MB available)
    char* ws = (char*)d_ws;
    double*   acc   = (double*)ws;                                   // 256 B
    _Float16* hh2   = (_Float16*)(ws + 256);                         // 32 MB
    _Float16* Wd2t  = (_Float16*)(ws + 256 + (size_t)32*1024*1024);  // 2 MB
    _Float16* Wd3t  = (_Float16*)(ws + 256 + (size_t)34*1024*1024);  // 6 MB
    // hh1 (fp16, 32 MB) lives in d_out scratch — dead before GEMM3 overwrites out
    _Float16* hh1   = (_Float16*)d_out;

    hipLaunchKernelGGL(init_acc, dim3(1), dim3(64), 0, stream, acc);

    hipLaunchKernelGGL(flow_kernel, dim3(BB/256, ZD), dim3(256), 0, stream,
                       e1, e2, interv, W1, b1, W2, b2, W3, b3, acc);

    hipLaunchKernelGGL(convT_kernel, dim3(DH/32, DH/32), dim3(256), 0, stream,
                       Wd2, Wd2t, DH, DH);
    hipLaunchKernelGGL(convT_kernel, dim3(DX/32, DH/32), dim3(256), 0, stream,
                       Wd3, Wd3t, DH, DX);

    hipLaunchKernelGGL(dec1_kernel, dim3(M2), dim3(256), 0, stream,
                       e1, e2, Wd1, bd1, hh1);

    hipLaunchKernelGGL((gemm_mfma<1,1>), dim3(DH/128, M2/128), dim3(256), 0, stream,
                       hh1, Wd2t, bd2, (void*)hh2, M2, DH, DH);

    hipLaunchKernelGGL((gemm_mfma<0,0>), dim3(DX/128, M2/128), dim3(256), 0, stream,
                       hh2, Wd3t, bd3, (void*)out, M2, DX, DH);

    hipLaunchKernelGGL(finalize_kernel, dim3(1), dim3(64), 0, stream, acc, out);
}

// Round 3
// 460.358 us; speedup vs baseline: 3.7427x; 1.1069x over previous
//
#include <hip/hip_runtime.h>
#include <cmath>

// Problem constants
#define BB   8192
#define ZD   16
#define DH   1024
#define DX   3072
#define M2   (2*BB)

static constexpr float LOG2PI_F = 1.8378770664093453f;   // log(2*pi)
static constexpr float CLAMP_F  = 1000000.0f;

using half8  = __attribute__((ext_vector_type(8))) _Float16;
using half4v = __attribute__((ext_vector_type(4))) _Float16;
using f32x4  = __attribute__((ext_vector_type(4))) float;

__device__ __forceinline__ float clampv(float x){
    return fminf(fmaxf(x, -CLAMP_F), CLAMP_F);
}

// async global->LDS, 16B per lane. LDS dest must be wave-uniform base + lane*16.
__device__ __forceinline__ void gload_lds16(const void* g, void* l){
    __builtin_amdgcn_global_load_lds(
        (const __attribute__((address_space(1))) unsigned int*)g,
        (__attribute__((address_space(3))) unsigned int*)l,
        16, 0, 0);
}

// ---------------------------------------------------------------------------
// Accumulator init / finalize
// ---------------------------------------------------------------------------
__global__ void init_acc(double* acc){
    if (threadIdx.x == 0) acc[0] = 0.0;
}

__global__ void finalize_kernel(const double* __restrict__ acc, float* __restrict__ out){
    if (threadIdx.x == 0){
        const double LOG17 = 2.8332133440562162; // log(17)
        const double log_p_I = -LOG17 * (double)BB;
        out[(size_t)2 * BB * DX] = (float)(acc[0] + log_p_I);
    }
}

// ---------------------------------------------------------------------------
// Flow network (unchanged — correctness-proven)
// ---------------------------------------------------------------------------
__global__ __launch_bounds__(256)
void flow_kernel(const float* __restrict__ e1, const float* __restrict__ e2,
                 const float* __restrict__ interv,
                 const float* __restrict__ W1, const float* __restrict__ b1,
                 const float* __restrict__ W2, const float* __restrict__ b2,
                 const float* __restrict__ W3, const float* __restrict__ b3,
                 double* __restrict__ acc)
{
    const int i = blockIdx.y;
    const int b = blockIdx.x * 256 + threadIdx.x;

    float ex[16];
    #pragma unroll
    for (int d = 0; d < 16; d += 4){
        const float4 v = *reinterpret_cast<const float4*>(&e1[(size_t)b*16 + d]);
        ex[d] = v.x; ex[d+1] = v.y; ex[d+2] = v.z; ex[d+3] = v.w;
    }

    float lp1 = 0.f;
    if (i == 0){
        #pragma unroll
        for (int d = 0; d < 16; ++d){
            const float t = -0.5f*ex[d]*ex[d] - 0.5f*LOG2PI_F;
            lp1 += clampv(t);
        }
    }

    #pragma unroll
    for (int d = 0; d < 16; ++d)
        if (d == i) ex[d] = 0.f;

    float h1[64];
    #pragma unroll
    for (int h = 0; h < 64; h += 4){
        const float4 bv = *reinterpret_cast<const float4*>(&b1[i*64 + h]);
        h1[h] = bv.x; h1[h+1] = bv.y; h1[h+2] = bv.z; h1[h+3] = bv.w;
    }
    for (int d = 0; d < 16; ++d){
        const float c = ex[d];
        const float* w = &W1[((size_t)i*16 + d)*64];
        #pragma unroll
        for (int h = 0; h < 64; h += 4){
            const float4 wv = *reinterpret_cast<const float4*>(&w[h]);
            h1[h]   = fmaf(c, wv.x, h1[h]);
            h1[h+1] = fmaf(c, wv.y, h1[h+1]);
            h1[h+2] = fmaf(c, wv.z, h1[h+2]);
            h1[h+3] = fmaf(c, wv.w, h1[h+3]);
        }
    }
    #pragma unroll
    for (int h = 0; h < 64; ++h) h1[h] = fmaxf(h1[h], 0.f);

    float hk[64];
    #pragma unroll
    for (int k = 0; k < 64; k += 4){
        const float4 bv = *reinterpret_cast<const float4*>(&b2[i*64 + k]);
        hk[k] = bv.x; hk[k+1] = bv.y; hk[k+2] = bv.z; hk[k+3] = bv.w;
    }
    for (int h = 0; h < 64; ++h){
        const float hv = h1[h];
        const float* w = &W2[((size_t)i*64 + h)*64];
        #pragma unroll
        for (int k = 0; k < 64; k += 4){
            const float4 wv = *reinterpret_cast<const float4*>(&w[k]);
            hk[k]   = fmaf(hv, wv.x, hk[k]);
            hk[k+1] = fmaf(hv, wv.y, hk[k+1]);
            hk[k+2] = fmaf(hv, wv.z, hk[k+2]);
            hk[k+3] = fmaf(hv, wv.w, hk[k+3]);
        }
    }
    #pragma unroll
    for (int k = 0; k < 64; ++k) hk[k] = fmaxf(hk[k], 0.f);

    float p0 = b3[i*2 + 0];
    float p1 = b3[i*2 + 1];
    for (int k = 0; k < 64; ++k){
        const float2 wv = *reinterpret_cast<const float2*>(&W3[((size_t)i*64 + k)*2]);
        p0 = fmaf(hk[k], wv.x, p0);
        p1 = fmaf(hk[k], wv.y, p1);
    }

    const float shift = p0;
    const float sp    = (p1 > 20.f) ? p1 : log1pf(expf(p1));
    const float scale = sp + 0.2f;
    float z = (e2[(size_t)b*16 + i] - shift) / scale;
    z = clampv(z);
    const float mask = interv[(size_t)b*17 + i + 1];
    const float term = (-0.5f*z*z - 0.5f*LOG2PI_F - logf(scale)) * mask;

    double v = (double)term + (double)lp1;

    #pragma unroll
    for (int off = 32; off; off >>= 1) v += __shfl_down(v, off, 64);
    __shared__ double sred[4];
    if ((threadIdx.x & 63) == 0) sred[threadIdx.x >> 6] = v;
    __syncthreads();
    if (threadIdx.x == 0){
        const double s = sred[0] + sred[1] + sred[2] + sred[3];
        atomicAdd(acc, s);
    }
}

// ---------------------------------------------------------------------------
// Transpose + fp32->fp16 convert: Wt[n][k] = (half)W[k][n]
// ---------------------------------------------------------------------------
__global__ __launch_bounds__(256)
void convT_kernel(const float* __restrict__ W, _Float16* __restrict__ Wt,
                  int K, int N)
{
    __shared__ float s[32][33];
    const int n0 = blockIdx.x * 32;
    const int k0 = blockIdx.y * 32;
    const int t  = threadIdx.x;
    const int r  = t >> 3;
    const int c4 = (t & 7) * 4;

    const float4 v = *reinterpret_cast<const float4*>(&W[(size_t)(k0 + r)*N + n0 + c4]);
    s[r][c4+0] = v.x; s[r][c4+1] = v.y; s[r][c4+2] = v.z; s[r][c4+3] = v.w;
    __syncthreads();

    half4v o;
    o[0] = (_Float16)s[c4+0][r];
    o[1] = (_Float16)s[c4+1][r];
    o[2] = (_Float16)s[c4+2][r];
    o[3] = (_Float16)s[c4+3][r];
    *reinterpret_cast<half4v*>(&Wt[(size_t)(n0 + r)*K + k0 + c4]) = o;
}

// ---------------------------------------------------------------------------
// Decoder layer 1: hh1 = relu(E @ Wd1 + bd1) as fp16
// ---------------------------------------------------------------------------
__global__ __launch_bounds__(256)
void dec1_kernel(const float* __restrict__ e1, const float* __restrict__ e2,
                 const float* __restrict__ Wd1, const float* __restrict__ bd1,
                 _Float16* __restrict__ hh1)
{
    const int r = blockIdx.x;
    const float* e = (r < BB) ? &e1[(size_t)r*16] : &e2[(size_t)(r - BB)*16];
    const int col = threadIdx.x * 4;
    float4 a = *reinterpret_cast<const float4*>(&bd1[col]);
    #pragma unroll
    for (int d = 0; d < 16; ++d){
        const float ev = e[d];
        const float4 w = *reinterpret_cast<const float4*>(&Wd1[(size_t)d*DH + col]);
        a.x = fmaf(ev, w.x, a.x);
        a.y = fmaf(ev, w.y, a.y);
        a.z = fmaf(ev, w.z, a.z);
        a.w = fmaf(ev, w.w, a.w);
    }
    half4v o;
    o[0] = (_Float16)fmaxf(a.x, 0.f);
    o[1] = (_Float16)fmaxf(a.y, 0.f);
    o[2] = (_Float16)fmaxf(a.z, 0.f);
    o[3] = (_Float16)fmaxf(a.w, 0.f);
    *reinterpret_cast<half4v*>(&hh1[(size_t)r*DH + col]) = o;
}

// ---------------------------------------------------------------------------
// fp16 MFMA GEMM, 256x256 tile, BK=32, 8 waves (2M x 4N), 512 threads.
// 4-deep rotating LDS buffers (4 x 32KB = 128KB): stage tile t+2 while
// computing tile t -> concurrent iters {t,t+1} read bufs {t,t+1}%4 and
// write {t+2,t+3}%4, all disjoint. One raw s_barrier + counted vmcnt(4)
// per K-step; vmcnt never drains to 0 in the main loop (T3+T4).
// Chunk swizzle c^=((row>>1)&3) on both stage-source and ds_read (rule #21),
// verified in round 2. A:[M][K] fp16, Bt:[N][K] fp16.
// ---------------------------------------------------------------------------
template<int NRELU, int OUT_HALF>
__global__ __launch_bounds__(512, 2)
void gemm_mfma256(const _Float16* __restrict__ A,
                  const _Float16* __restrict__ Bt,
                  const float* __restrict__ bias,
                  void* __restrict__ Cout,
                  int M, int N, int K)
{
    __shared__ _Float16 lds[4 * 2 * 8192];   // 128 KiB: [buf][A 16KB | B 16KB]

    const int tid  = threadIdx.x;
    const int lane = tid & 63;
    const int wid  = tid >> 6;        // 0..7
    const int wr   = wid >> 2;        // 0..1 (M)
    const int wc   = wid & 3;         // 0..3 (N)

    // T1: bijective XCD swizzle (nwg % 8 == 0 for all our grids)
    const int gx  = gridDim.x;
    const int nwg = gx * gridDim.y;
    const int orig = blockIdx.y * gx + blockIdx.x;
    const int swz  = (orig & 7) * (nwg >> 3) + (orig >> 3);
    const int brow = (swz / gx) * 256;
    const int bcol = (swz % gx) * 256;

    f32x4 acc[8][4];
    #pragma unroll
    for (int mb = 0; mb < 8; ++mb)
        #pragma unroll
        for (int nb = 0; nb < 4; ++nb)
            acc[mb][nb] = (f32x4){0.f, 0.f, 0.f, 0.f};

    // ---- staging addressing (2 loads each for A and B per K-step) ----
    // LDS-linear chunk (j*512+tid) -> row=chunk>>2, c=chunk&3; source chunk
    // is inverse-swizzled: c ^ ((row>>1)&3).
    size_t baseA[2], baseB[2];
    int    dstA[2],  dstB[2];
    #pragma unroll
    for (int j = 0; j < 2; ++j){
        const int cl  = j*512 + tid;
        const int row = cl >> 2;
        const int c   = cl & 3;
        const int sc  = c ^ ((row >> 1) & 3);
        baseA[j] = (size_t)(brow + row)*K + sc*8;
        baseB[j] = (size_t)(bcol + row)*K + sc*8;
        dstA[j]  = cl * 16;            // bytes within buf's A region
        dstB[j]  = 16384 + cl * 16;    // bytes within buf's B region
    }

    // ---- fragment read offsets (swizzled), bytes within a buf ----
    int offA[8], offB[4];
    #pragma unroll
    for (int mb = 0; mb < 8; ++mb){
        const int row = wr*128 + mb*16 + (lane & 15);
        const int c   = (lane >> 4) ^ ((row >> 1) & 3);
        offA[mb] = row*64 + c*16;
    }
    #pragma unroll
    for (int nb = 0; nb < 4; ++nb){
        const int row = wc*64 + nb*16 + (lane & 15);
        const int c   = (lane >> 4) ^ ((row >> 1) & 3);
        offB[nb] = 16384 + row*64 + c*16;
    }

    const int NT = K >> 5;   // 32 K-steps for K=1024

    auto STAGE = [&](int kt){
        char* lb = (char*)lds + (size_t)(kt & 3) * 32768;
        const size_t k0 = (size_t)kt * 32;
        gload_lds16(A  + baseA[0] + k0, lb + dstA[0]);
        gload_lds16(A  + baseA[1] + k0, lb + dstA[1]);
        gload_lds16(Bt + baseB[0] + k0, lb + dstB[0]);
        gload_lds16(Bt + baseB[1] + k0, lb + dstB[1]);
    };

    // prologue: tiles 0 and 1 in flight (8 loads)
    STAGE(0);
    STAGE(1);

    for (int t = 0; t < NT; ++t){
        __builtin_amdgcn_sched_barrier(0);   // pin iter boundary (rule #18)
        if (t < NT-1) asm volatile("s_waitcnt vmcnt(4)" ::: "memory");
        else          asm volatile("s_waitcnt vmcnt(0)" ::: "memory");
        asm volatile("s_barrier" ::: "memory");

        if (t + 2 < NT) STAGE(t + 2);

        const char* base = (const char*)lds + (size_t)(t & 3) * 32768;
        half8 af[8], bf[4];
        #pragma unroll
        for (int mb = 0; mb < 8; ++mb)
            af[mb] = *reinterpret_cast<const half8*>(base + offA[mb]);
        #pragma unroll
        for (int nb = 0; nb < 4; ++nb)
            bf[nb] = *reinterpret_cast<const half8*>(base + offB[nb]);

        __builtin_amdgcn_s_setprio(1);
        #pragma unroll
        for (int mb = 0; mb < 8; ++mb)
            #pragma unroll
            for (int nb = 0; nb < 4; ++nb)
                acc[mb][nb] = __builtin_amdgcn_mfma_f32_16x16x32_f16(
                                  af[mb], bf[nb], acc[mb][nb], 0, 0, 0);
        __builtin_amdgcn_s_setprio(0);
    }

    // epilogue: C/D layout col=lane&15, row=(lane>>4)*4+reg  [m89/m91]
    const int lc  = lane & 15;
    const int lr4 = (lane >> 4) * 4;
    #pragma unroll
    for (int nb = 0; nb < 4; ++nb){
        const int col = bcol + wc*64 + nb*16 + lc;
        const float bv = bias[col];
        #pragma unroll
        for (int mb = 0; mb < 8; ++mb){
            const int rowg = brow + wr*128 + mb*16 + lr4;
            #pragma unroll
            for (int r = 0; r < 4; ++r){
                float v = acc[mb][nb][r] + bv;
                if (NRELU) v = fmaxf(v, 0.f);
                if (OUT_HALF)
                    ((_Float16*)Cout)[(size_t)(rowg + r)*N + col] = (_Float16)v;
                else
                    ((float*)Cout)[(size_t)(rowg + r)*N + col] = v;
            }
        }
    }
}

// ---------------------------------------------------------------------------
// launcher
// ---------------------------------------------------------------------------
extern "C" void kernel_launch(void* const* d_in, const int* in_sizes, int n_in,
                              void* d_out, int out_size, void* d_ws, size_t ws_size,
                              hipStream_t stream)
{
    const float* e1     = (const float*)d_in[0];
    const float* e2     = (const float*)d_in[1];
    const float* interv = (const float*)d_in[2];
    const float* W1     = (const float*)d_in[3];
    const float* b1     = (const float*)d_in[4];
    const float* W2     = (const float*)d_in[5];
    const float* b2     = (const float*)d_in[6];
    const float* W3     = (const float*)d_in[7];
    const float* b3     = (const float*)d_in[8];
    const float* Wd1    = (const float*)d_in[9];
    const float* bd1    = (const float*)d_in[10];
    const float* Wd2    = (const float*)d_in[11];
    const float* bd2    = (const float*)d_in[12];
    const float* Wd3    = (const float*)d_in[13];
    const float* bd3    = (const float*)d_in[14];

    float* out = (float*)d_out;

    // workspace map (~40.25 MB)
    char* ws = (char*)d_ws;
    double*   acc   = (double*)ws;                                   // 256 B
    _Float16* hh2   = (_Float16*)(ws + 256);                         // 32 MB
    _Float16* Wd2t  = (_Float16*)(ws + 256 + (size_t)32*1024*1024);  // 2 MB
    _Float16* Wd3t  = (_Float16*)(ws + 256 + (size_t)34*1024*1024);  // 6 MB
    _Float16* hh1   = (_Float16*)d_out;  // scratch in d_out, dead before GEMM3

    hipLaunchKernelGGL(init_acc, dim3(1), dim3(64), 0, stream, acc);

    hipLaunchKernelGGL(flow_kernel, dim3(BB/256, ZD), dim3(256), 0, stream,
                       e1, e2, interv, W1, b1, W2, b2, W3, b3, acc);

    hipLaunchKernelGGL(convT_kernel, dim3(DH/32, DH/32), dim3(256), 0, stream,
                       Wd2, Wd2t, DH, DH);
    hipLaunchKernelGGL(convT_kernel, dim3(DX/32, DH/32), dim3(256), 0, stream,
                       Wd3, Wd3t, DH, DX);

    hipLaunchKernelGGL(dec1_kernel, dim3(M2), dim3(256), 0, stream,
                       e1, e2, Wd1, bd1, hh1);

    hipLaunchKernelGGL((gemm_mfma256<1,1>), dim3(DH/256, M2/256), dim3(512), 0, stream,
                       hh1, Wd2t, bd2, (void*)hh2, M2, DH, DH);

    hipLaunchKernelGGL((gemm_mfma256<0,0>), dim3(DX/256, M2/256), dim3(512), 0, stream,
                       hh2, Wd3t, bd3, (void*)out, M2, DX, DH);

    hipLaunchKernelGGL(finalize_kernel, dim3(1), dim3(64), 0, stream, acc, out);
}